// Round 16
// baseline (381.441 us; speedup 1.0000x reference)
//
#include <hip/hip_runtime.h>
#include <stdint.h>

typedef float f32x4 __attribute__((ext_vector_type(4)));
typedef __bf16 bf16x8 __attribute__((ext_vector_type(8)));
typedef unsigned short u16;
typedef unsigned short u16x8 __attribute__((ext_vector_type(8)));

__device__ __forceinline__ u16 f2b(float f) {
    union { float f; unsigned u; } v; v.f = f;
    return (u16)((v.u + 0x7fffu + ((v.u >> 16) & 1u)) >> 16);
}
__device__ __forceinline__ float b2f(u16 b) {
    union { unsigned u; float f; } v; v.u = ((unsigned)b) << 16;
    return v.f;
}
__device__ __forceinline__ u16 f2b_hw(float f) {      // native convert (1 VALU op)
    __bf16 h = (__bf16)f;
    return __builtin_bit_cast(u16, h);
}

__device__ __forceinline__ void gload16(const u16* g, u16* s) {
    __builtin_amdgcn_global_load_lds((const __attribute__((address_space(1))) void*)g,
                                     (__attribute__((address_space(3))) void*)s, 16, 0, 0);
}

// ---------------- cast fp32 -> bf16 (8 elems/thread) ----------------
__global__ __launch_bounds__(256) void k_cast(const float* __restrict__ src, u16* __restrict__ dst, int n) {
    int i = (blockIdx.x * 256 + threadIdx.x) * 8;
    if (i >= n) return;
    const float4* s = (const float4*)(src + i);
    float4 a = s[0], b = s[1];
    u16x8 o;
    o[0] = f2b(a.x); o[1] = f2b(a.y); o[2] = f2b(a.z); o[3] = f2b(a.w);
    o[4] = f2b(b.x); o[5] = f2b(b.y); o[6] = f2b(b.z); o[7] = f2b(b.w);
    *(u16x8*)(dst + i) = o;
}

// ---------- transpose + cast: src[R][C] f32 -> dst[C][R] bf16, u32-packed writes ----------
__global__ __launch_bounds__(256) void k_transpose(const float* __restrict__ src, u16* __restrict__ dst,
                                                   int R, int C) {
    __shared__ float tile[64][65];
    int c0 = blockIdx.x * 64, r0 = blockIdx.y * 64;
    int tx = threadIdx.x & 63, ty = threadIdx.x >> 6;
    #pragma unroll
    for (int r = ty; r < 64; r += 4)
        tile[r][tx] = src[(size_t)(r0 + r) * C + (c0 + tx)];
    __syncthreads();
    int hx = threadIdx.x & 31, ty8 = threadIdx.x >> 5;
    #pragma unroll
    for (int r = ty8; r < 64; r += 8) {
        unsigned v = (unsigned)f2b(tile[hx * 2][r]) | ((unsigned)f2b(tile[hx * 2 + 1][r]) << 16);
        *(unsigned*)&dst[(size_t)(c0 + r) * R + (r0 + hx * 2)] = v;   // 256B/wave, full line
    }
}

// ------------- bf16 transpose: QKVb V-columns -> VT[8][128][2048] -------------
__global__ __launch_bounds__(256) void k_vt(const u16* __restrict__ QKV, u16* __restrict__ VT) {
    __shared__ u16 tile[64][66];
    int kh = blockIdx.z;
    int s0 = blockIdx.y * 64;
    int d0 = blockIdx.x * 64;
    int tx = threadIdx.x & 63, ty = threadIdx.x >> 6;
    #pragma unroll
    for (int r = ty; r < 64; r += 4)
        tile[r][tx] = QKV[(size_t)(s0 + r) * 6144 + 5120 + kh * 128 + d0 + tx];
    __syncthreads();
    #pragma unroll
    for (int r = ty; r < 64; r += 4)
        VT[(size_t)kh * 262144 + (size_t)(d0 + r) * 2048 + s0 + tx] = tile[tx][r];
}

// ====== (MFR*32) x (NFR*64) GEMM core, BK=64, 8 waves (2M x 4N), full-tile prefetch ======
#define STAGE_A(h) do { \
    _Pragma("unroll") for (int i_ = 0; i_ < MFR / 4; ++i_) \
        gload16(gA + (size_t)((h) * (MFR * 16) + i_ * 8) * K + kn, &Ah[nb][h][w * (MFR * 2) + i_ * 8][0]); \
} while (0)
#define STAGE_B1(h) gload16(gB + (size_t)((h) * 64) * K + kn, &Bh[nb][h][w * 8][0])
#define STAGE_ALL do { \
    _Pragma("unroll") for (int h_ = 0; h_ < 2; ++h_) STAGE_A(h_); \
    _Pragma("unroll") for (int h_ = 0; h_ < NFR; ++h_) STAGE_B1(h_); } while (0)
#define RD_AF(MH, AF) do { \
    _Pragma("unroll") for (int mm = 0; mm < MFR / 2; ++mm) \
    _Pragma("unroll") for (int x = 0; x < 2; ++x) \
        AF[mm][x] = *(const bf16x8*)&Ah[c][wm][((MH) * (MFR / 2) + mm) * 16 + lr][(x * 32 + lk) ^ swz]; } while (0)
#define RD_BF1(NF) do { \
    int bc_ = wn * (NFR * 16) + (NF) * 16; \
    _Pragma("unroll") for (int x = 0; x < 2; ++x) \
        bfr[NF][x] = *(const bf16x8*)&Bh[c][bc_ >> 6][(bc_ & 63) + lr][(x * 32 + lk) ^ swz]; } while (0)
#define MMAH(MH, NF, AF) do { \
    _Pragma("unroll") for (int x = 0; x < 2; ++x) \
    _Pragma("unroll") for (int mm = 0; mm < MFR / 2; ++mm) \
        acc[(MH) * (MFR / 2) + mm][NF] = __builtin_amdgcn_mfma_f32_16x16x32_bf16( \
            AF[mm][x], bfr[NF][x], acc[(MH) * (MFR / 2) + mm][NF], 0, 0, 0); } while (0)

template <int MFR, int NFR, typename OutT>
__device__ __forceinline__ void gemm_core(const u16* __restrict__ A, const u16* __restrict__ Bt,
                                          OutT* __restrict__ C, int K, int ldc, int m0, int n0) {
    __shared__ u16 Ah[2][2][MFR * 16][64];
    __shared__ u16 Bh[2][NFR][64][64];
    constexpr int LPT = MFR / 2 + NFR;   // loads/thread/tile
    int tid = threadIdx.x;
    int l = tid & 63, w = tid >> 6;
    int wm = w >> 2, wn = w & 3;
    int lr = l & 15, lg = l >> 4, lk = lg * 8;
    int swz = (lr & 7) << 3;
    int srow8 = l >> 3;
    int scol = ((l & 7) ^ srow8) * 8;
    const u16* gA = A  + (size_t)(m0 + w * (MFR * 2) + srow8) * K + scol;
    const u16* gB = Bt + (size_t)(n0 + w * 8 + srow8) * K + scol;
    f32x4 acc[MFR][NFR] = {};
    int NT = K >> 6;

    {   // prologue: stage tile 0 into buf 0
        int kn = 0, nb = 0;
        STAGE_ALL;
    }

    #pragma unroll 2
    for (int t = 0; t < NT; ++t) {
        int c = t & 1, nb = c ^ 1;
        int kn = (t + 1) << 6;
        bool last = (t == NT - 1);
        bf16x8 af0[MFR / 2][2], af1[MFR / 2][2], bfr[NFR][2];
        // ---- tile top: issue ALL loads of tile t+1; drain exactly tile t's ----
        if (!last) {
            STAGE_ALL;
            asm volatile("s_waitcnt vmcnt(%0)" :: "n"(LPT) : "memory");
        } else {
            asm volatile("s_waitcnt vmcnt(0)" ::: "memory");
        }
        __builtin_amdgcn_s_barrier();
        // ---- interleaved reads + MFMA (counted lgkmcnt by compiler) ----
        RD_AF(0, af0);
        #pragma unroll
        for (int nf = 0; nf < NFR; ++nf) {
            RD_BF1(nf);
            __builtin_amdgcn_s_setprio(1);
            MMAH(0, nf, af0);
            __builtin_amdgcn_s_setprio(0);
        }
        RD_AF(1, af1);
        __builtin_amdgcn_s_setprio(1);
        #pragma unroll
        for (int nf = 0; nf < NFR; ++nf)
            MMAH(1, nf, af1);
        __builtin_amdgcn_s_setprio(0);
        // ---- tile end: all reads of buf c sampled; next tile may overwrite ----
        __builtin_amdgcn_s_barrier();
    }

    #pragma unroll
    for (int m = 0; m < MFR; ++m)
        #pragma unroll
        for (int n = 0; n < NFR; ++n)
            #pragma unroll
            for (int e = 0; e < 4; ++e) {
                int row = m0 + wm * (MFR * 16) + m * 16 + lg * 4 + e;
                int col = n0 + wn * (NFR * 16) + n * 16 + lr;
                if constexpr (sizeof(OutT) == 4)
                    C[(size_t)row * ldc + col] = acc[m][n][e];
                else
                    C[(size_t)row * ldc + col] = f2b(acc[m][n][e]);
            }
}

// QKV fused: QKVb[2048][6144]. 128x192 tiles, grid 512 = 16 m x 32 n -> 2 blocks/CU (LDS 80KB).
__global__ __launch_bounds__(512, 2) void k_gemm_qkv(const u16* __restrict__ hsb,
        const u16* __restrict__ WqkvT, u16* __restrict__ QKVb) {
    int bid = blockIdx.x;
    int ord = (bid & 7) * 64 + (bid >> 3);   // XCD swizzle (512 % 8 == 0)
    int mt = ord >> 5, nt = ord & 31;
    gemm_core<4, 3, u16>(hsb, WqkvT, QKVb, 4096, 6144, mt * 128, nt * 192);
}

// Out-proj: 128x128 tiles, grid 512 = 16 m x 32 n -> 2 blocks/CU (LDS 64KB).
__global__ __launch_bounds__(512, 2) void k_gemm_out(const u16* __restrict__ Ob, const u16* __restrict__ WoT,
                                                     float* __restrict__ out) {
    int bid = blockIdx.x;
    int ord = (bid & 7) * 64 + (bid >> 3);   // XCD swizzle (512 % 8 == 0)
    int mt = ord >> 5, nt = ord & 31;
    gemm_core<4, 2, float>(Ob, WoT, out, 4096, 4096, mt * 128, nt * 128);
}

// ---------------- RoPE in-place on QKVb: Q (32 heads) and K (8 heads) ----------------
__global__ __launch_bounds__(256) void k_rope(u16* __restrict__ QKV) {
    int t = blockIdx.x * 256 + threadIdx.x;
    int i = t & 63;
    int rest = t >> 6;
    int head = rest % 40;
    int s = rest / 40;
    if (s >= 2048) return;
    u16* base = (head < 32) ? (QKV + (size_t)s * 6144 + head * 128)
                            : (QKV + (size_t)s * 6144 + 4096 + (head - 32) * 128);
    float inv = exp2f((float)i * (-13.287712379549449f / 64.0f));
    float fr = (float)s * inv;
    float sn, cs;
    sincosf(fr, &sn, &cs);
    float x1 = b2f(base[i]), x2 = b2f(base[i + 64]);
    base[i]      = f2b(x1 * cs - x2 * sn);
    base[i + 64] = f2b(x2 * cs + x1 * sn);
}

// ---------------- Flash attention v6: max-free softmax + 3 blocks/CU ----------------
// K single-buffered (Kl 16KB) -> LDS 49.4KB -> 3 blocks/CU (12 waves, +50% TLP to hide
// drain latency). 3 barriers/tile: top vmcnt(0)+bar publishes K(t)&V(t); after QK+P-write,
// bar#2 (all Kl reads retired) gates stage K(t+1); vmcnt(4)+bar#3 gates PV (V(t) drained,
// K(t+1) stays in flight).
__global__ __launch_bounds__(256, 3) void k_attn(const u16* __restrict__ QKV,
                                                 const u16* __restrict__ VT, u16* __restrict__ O) {
    __shared__ u16 Kl[64][128];      // 16 KB (single buffer)
    __shared__ u16 VTl[128][64];     // 16 KB
    __shared__ u16 Pl[4][32][68];    // 17 KB
    int bid = blockIdx.x;
    int kh = bid & 7;                // XCD-affine kv-head
    int x = bid >> 3;
    int j = x >> 2;
    int h = kh * 4 + (x & 3);
    int qb = (j < 8) ? j : 23 - j;   // pairs (qb, 15-qb): balanced work
    int q0 = qb * 128;
    int t = threadIdx.x, l = t & 63, w = t >> 6;
    int lr = l & 15, lg = l >> 4;
    const float cexp = 0.12751742f;  // log2(e)/sqrt(128)
    const u16* Kh = QKV + 4096 + kh * 128;         // row stride 6144
    const u16* VTh = VT + (size_t)kh * 262144;     // [128][2048]

#define ATT_STAGE_K(KV0) do { \
    _Pragma("unroll") for (int i_ = 0; i_ < 4; ++i_) { \
        int r0_ = w * 16 + i_ * 4; \
        int row_ = r0_ + (l >> 4); \
        gload16(Kh + (size_t)((KV0) + row_) * 6144 + ((l & 15) ^ (row_ & 7)) * 8, \
                &Kl[r0_][0]); \
    } } while (0)
#define ATT_STAGE_V(KV0) do { \
    _Pragma("unroll") for (int i_ = 0; i_ < 4; ++i_) { \
        int r0_ = w * 32 + i_ * 8; \
        int row_ = r0_ + (l >> 3); \
        gload16(VTh + (size_t)row_ * 2048 + (KV0) + ((l & 7) ^ (row_ & 7)) * 8, \
                &VTl[r0_][0]); \
    } } while (0)

    bf16x8 qf[2][4];
    #pragma unroll
    for (int rb = 0; rb < 2; ++rb) {
        size_t qoff = (size_t)(q0 + w * 32 + rb * 16 + lr) * 6144 + h * 128 + lg * 8;
        #pragma unroll
        for (int d = 0; d < 4; ++d)
            qf[rb][d] = *(const bf16x8*)(QKV + qoff + d * 32);
    }
    bf16x8 ones;
    #pragma unroll
    for (int i = 0; i < 8; ++i) ones[i] = (__bf16)1.0f;

    f32x4 oacc[2][8] = {};
    f32x4 osum[2] = {};

    int ntiles = 2 * qb + 2;
    int rowmax = q0 + w * 32 + 31;

    ATT_STAGE_K(0);                  // prologue: K tile 0

    for (int kt = 0; kt < ntiles; ++kt) {
        int kv0 = kt * 64;
        bool compute = (kv0 <= rowmax);
        bool more = (kt + 1 < ntiles);
        // ---- top: K(t) (+ V(t-1) leftovers) drained; publish to all waves ----
        asm volatile("s_waitcnt vmcnt(0)" ::: "memory");
        __builtin_amdgcn_s_barrier();
        ATT_STAGE_V(kv0);
        __builtin_amdgcn_sched_barrier(0);

        f32x4 sacc[2][4] = {};
        if (compute) {
            // ---- QK^T from Kl: d-slice OUTER (acc-dependency cover) ----
            #pragma unroll
            for (int d = 0; d < 4; ++d) {
                bf16x8 kf[4];
                #pragma unroll
                for (int cb = 0; cb < 4; ++cb)
                    kf[cb] = *(const bf16x8*)&Kl[cb * 16 + lr][((d * 4 + lg) ^ (lr & 7)) * 8];
                #pragma unroll
                for (int cb = 0; cb < 4; ++cb) {
                    sacc[0][cb] = __builtin_amdgcn_mfma_f32_16x16x32_bf16(qf[0][d], kf[cb], sacc[0][cb], 0, 0, 0);
                    sacc[1][cb] = __builtin_amdgcn_mfma_f32_16x16x32_bf16(qf[1][d], kf[cb], sacc[1][cb], 0, 0, 0);
                }
            }
            if (kt >= 2 * qb) {
                #pragma unroll
                for (int rb = 0; rb < 2; ++rb)
                    #pragma unroll
                    for (int cb = 0; cb < 4; ++cb)
                        #pragma unroll
                        for (int e = 0; e < 4; ++e) {
                            int row = q0 + w * 32 + rb * 16 + lg * 4 + e;
                            int col = kv0 + cb * 16 + lr;
                            if (col > row) sacc[rb][cb][e] = -3.0e38f;
                        }
            }
            // ---- P = exp2(S*c), native bf16 convert, straight to LDS ----
            #pragma unroll
            for (int rb = 0; rb < 2; ++rb)
                #pragma unroll
                for (int cb = 0; cb < 4; ++cb)
                    #pragma unroll
                    for (int e = 0; e < 4; ++e)
                        Pl[w][rb * 16 + lg * 4 + e][cb * 16 + lr] =
                            f2b_hw(exp2f(sacc[rb][cb][e] * cexp));
        }
        // ---- bar#2: all waves' Kl reads retired -> safe to overwrite Kl ----
        __builtin_amdgcn_s_barrier();
        if (more) ATT_STAGE_K(kv0 + 64);
        // ---- bar#3: V(t) drained (K(t+1)'s 4 loads stay in flight) ----
        if (more) asm volatile("s_waitcnt vmcnt(4)" ::: "memory");
        else      asm volatile("s_waitcnt vmcnt(0)" ::: "memory");
        __builtin_amdgcn_s_barrier();
        if (compute) {
            asm volatile("s_waitcnt lgkmcnt(0)" ::: "memory");
            __builtin_amdgcn_sched_barrier(0);
            __builtin_amdgcn_s_setprio(1);
            #pragma unroll
            for (int ks = 0; ks < 2; ++ks) {
                bf16x8 pf0 = *(const bf16x8*)&Pl[w][lr][ks * 32 + lg * 8];
                bf16x8 pf1 = *(const bf16x8*)&Pl[w][16 + lr][ks * 32 + lg * 8];
                osum[0] = __builtin_amdgcn_mfma_f32_16x16x32_bf16(pf0, ones, osum[0], 0, 0, 0);
                osum[1] = __builtin_amdgcn_mfma_f32_16x16x32_bf16(pf1, ones, osum[1], 0, 0, 0);
                #pragma unroll
                for (int db = 0; db < 8; ++db) {
                    bf16x8 vf = *(const bf16x8*)&VTl[db * 16 + lr][((ks * 4 + lg) ^ (lr & 7)) * 8];
                    oacc[0][db] = __builtin_amdgcn_mfma_f32_16x16x32_bf16(pf0, vf, oacc[0][db], 0, 0, 0);
                    oacc[1][db] = __builtin_amdgcn_mfma_f32_16x16x32_bf16(pf1, vf, oacc[1][db], 0, 0, 0);
                }
            }
            __builtin_amdgcn_s_setprio(0);
        }
    }
    #pragma unroll
    for (int rb = 0; rb < 2; ++rb)
        #pragma unroll
        for (int db = 0; db < 8; ++db)
            #pragma unroll
            for (int e = 0; e < 4; ++e) {
                int row = q0 + w * 32 + rb * 16 + lg * 4 + e;
                O[(size_t)row * 4096 + h * 128 + db * 16 + lr] = f2b(oacc[rb][db][e] / osum[rb][e]);
            }
#undef ATT_STAGE_K
#undef ATT_STAGE_V
}

extern "C" void kernel_launch(void* const* d_in, const int* in_sizes, int n_in,
                              void* d_out, int out_size, void* d_ws, size_t ws_size,
                              hipStream_t stream) {
    const float* hs = (const float*)d_in[0];
    const float* Wq = (const float*)d_in[1];
    const float* Wk = (const float*)d_in[2];
    const float* Wv = (const float*)d_in[3];
    const float* Wo = (const float*)d_in[4];
    float* out = (float*)d_out;
    char* ws = (char*)d_ws;
    // layout (peak 92.3 MB):
    u16* hsb   = (u16*)(ws);              // [2048][4096] 16.78MB; later Ob
    u16* WqkvT = (u16*)(ws + 16777216);   // [6144][4096] 50.33MB; later VTb+WoT
    u16* QKVb  = (u16*)(ws + 67108864);   // [2048][6144] 25.17MB

    k_cast<<<4096, 256, 0, stream>>>(hs, hsb, 2048 * 4096);
    k_transpose<<<dim3(64, 64), 256, 0, stream>>>(Wq, WqkvT, 4096, 4096);
    k_transpose<<<dim3(16, 64), 256, 0, stream>>>(Wk, WqkvT + (size_t)4096 * 4096, 4096, 1024);
    k_transpose<<<dim3(16, 64), 256, 0, stream>>>(Wv, WqkvT + (size_t)5120 * 4096, 4096, 1024);
    k_gemm_qkv<<<512, 512, 0, stream>>>(hsb, WqkvT, QKVb);
    k_rope<<<20480, 256, 0, stream>>>(QKVb);
    u16* VTb = WqkvT;                         // WqkvT dead after QKV gemm (4.19MB)
    k_vt<<<dim3(2, 32, 8), 256, 0, stream>>>(QKVb, VTb);
    u16* WoT = WqkvT + (size_t)2097152;       // +4.19MB region, 33.55MB, fits in WqkvT
    k_transpose<<<dim3(64, 64), 256, 0, stream>>>(Wo, WoT, 4096, 4096);
    u16* Ob = hsb;                            // hsb dead after QKV gemm
    k_attn<<<512, 256, 0, stream>>>(QKVb, VTb, Ob);
    k_gemm_out<<<512, 512, 0, stream>>>(Ob, WoT, out);
}

// Round 17
// 331.743 us; speedup vs baseline: 1.1498x; 1.1498x over previous
//
#include <hip/hip_runtime.h>
#include <stdint.h>

typedef float f32x4 __attribute__((ext_vector_type(4)));
typedef __bf16 bf16x8 __attribute__((ext_vector_type(8)));
typedef unsigned short u16;
typedef unsigned short u16x8 __attribute__((ext_vector_type(8)));

__device__ __forceinline__ u16 f2b(float f) {
    union { float f; unsigned u; } v; v.f = f;
    return (u16)((v.u + 0x7fffu + ((v.u >> 16) & 1u)) >> 16);
}
__device__ __forceinline__ float b2f(u16 b) {
    union { unsigned u; float f; } v; v.u = ((unsigned)b) << 16;
    return v.f;
}
__device__ __forceinline__ u16 f2b_hw(float f) {      // native convert (1 VALU op)
    __bf16 h = (__bf16)f;
    return __builtin_bit_cast(u16, h);
}

__device__ __forceinline__ void gload16(const u16* g, u16* s) {
    __builtin_amdgcn_global_load_lds((const __attribute__((address_space(1))) void*)g,
                                     (__attribute__((address_space(3))) void*)s, 16, 0, 0);
}

// ---------------- cast fp32 -> bf16 (8 elems/thread) ----------------
__global__ __launch_bounds__(256) void k_cast(const float* __restrict__ src, u16* __restrict__ dst, int n) {
    int i = (blockIdx.x * 256 + threadIdx.x) * 8;
    if (i >= n) return;
    const float4* s = (const float4*)(src + i);
    float4 a = s[0], b = s[1];
    u16x8 o;
    o[0] = f2b(a.x); o[1] = f2b(a.y); o[2] = f2b(a.z); o[3] = f2b(a.w);
    o[4] = f2b(b.x); o[5] = f2b(b.y); o[6] = f2b(b.z); o[7] = f2b(b.w);
    *(u16x8*)(dst + i) = o;
}

// ---------- transpose + cast: src[R][C] f32 -> dst[C][R] bf16, u32-packed writes ----------
__global__ __launch_bounds__(256) void k_transpose(const float* __restrict__ src, u16* __restrict__ dst,
                                                   int R, int C) {
    __shared__ float tile[64][65];
    int c0 = blockIdx.x * 64, r0 = blockIdx.y * 64;
    int tx = threadIdx.x & 63, ty = threadIdx.x >> 6;
    #pragma unroll
    for (int r = ty; r < 64; r += 4)
        tile[r][tx] = src[(size_t)(r0 + r) * C + (c0 + tx)];
    __syncthreads();
    int hx = threadIdx.x & 31, ty8 = threadIdx.x >> 5;
    #pragma unroll
    for (int r = ty8; r < 64; r += 8) {
        unsigned v = (unsigned)f2b(tile[hx * 2][r]) | ((unsigned)f2b(tile[hx * 2 + 1][r]) << 16);
        *(unsigned*)&dst[(size_t)(c0 + r) * R + (r0 + hx * 2)] = v;   // 256B/wave, full line
    }
}

// ------------- bf16 transpose: QKVb V-columns -> VT[8][128][2048] -------------
__global__ __launch_bounds__(256) void k_vt(const u16* __restrict__ QKV, u16* __restrict__ VT) {
    __shared__ u16 tile[64][66];
    int kh = blockIdx.z;
    int s0 = blockIdx.y * 64;
    int d0 = blockIdx.x * 64;
    int tx = threadIdx.x & 63, ty = threadIdx.x >> 6;
    #pragma unroll
    for (int r = ty; r < 64; r += 4)
        tile[r][tx] = QKV[(size_t)(s0 + r) * 6144 + 5120 + kh * 128 + d0 + tx];
    __syncthreads();
    #pragma unroll
    for (int r = ty; r < 64; r += 4)
        VT[(size_t)kh * 262144 + (size_t)(d0 + r) * 2048 + s0 + tx] = tile[tx][r];
}

// ====== (MFR*32) x (NFR*64) GEMM core, BK=64, 8 waves (2M x 4N), full-tile prefetch ======
#define STAGE_A(h) do { \
    _Pragma("unroll") for (int i_ = 0; i_ < MFR / 4; ++i_) \
        gload16(gA + (size_t)((h) * (MFR * 16) + i_ * 8) * K + kn, &Ah[nb][h][w * (MFR * 2) + i_ * 8][0]); \
} while (0)
#define STAGE_B1(h) gload16(gB + (size_t)((h) * 64) * K + kn, &Bh[nb][h][w * 8][0])
#define STAGE_ALL do { \
    _Pragma("unroll") for (int h_ = 0; h_ < 2; ++h_) STAGE_A(h_); \
    _Pragma("unroll") for (int h_ = 0; h_ < NFR; ++h_) STAGE_B1(h_); } while (0)
#define RD_AF(MH, AF) do { \
    _Pragma("unroll") for (int mm = 0; mm < MFR / 2; ++mm) \
    _Pragma("unroll") for (int x = 0; x < 2; ++x) \
        AF[mm][x] = *(const bf16x8*)&Ah[c][wm][((MH) * (MFR / 2) + mm) * 16 + lr][(x * 32 + lk) ^ swz]; } while (0)
#define RD_BF1(NF) do { \
    int bc_ = wn * (NFR * 16) + (NF) * 16; \
    _Pragma("unroll") for (int x = 0; x < 2; ++x) \
        bfr[NF][x] = *(const bf16x8*)&Bh[c][bc_ >> 6][(bc_ & 63) + lr][(x * 32 + lk) ^ swz]; } while (0)
#define MMAH(MH, NF, AF) do { \
    _Pragma("unroll") for (int x = 0; x < 2; ++x) \
    _Pragma("unroll") for (int mm = 0; mm < MFR / 2; ++mm) \
        acc[(MH) * (MFR / 2) + mm][NF] = __builtin_amdgcn_mfma_f32_16x16x32_bf16( \
            AF[mm][x], bfr[NF][x], acc[(MH) * (MFR / 2) + mm][NF], 0, 0, 0); } while (0)

template <int MFR, int NFR, typename OutT>
__device__ __forceinline__ void gemm_core(const u16* __restrict__ A, const u16* __restrict__ Bt,
                                          OutT* __restrict__ C, int K, int ldc, int m0, int n0) {
    __shared__ u16 Ah[2][2][MFR * 16][64];
    __shared__ u16 Bh[2][NFR][64][64];
    constexpr int LPT = MFR / 2 + NFR;   // loads/thread/tile
    int tid = threadIdx.x;
    int l = tid & 63, w = tid >> 6;
    int wm = w >> 2, wn = w & 3;
    int lr = l & 15, lg = l >> 4, lk = lg * 8;
    int swz = (lr & 7) << 3;
    int srow8 = l >> 3;
    int scol = ((l & 7) ^ srow8) * 8;
    const u16* gA = A  + (size_t)(m0 + w * (MFR * 2) + srow8) * K + scol;
    const u16* gB = Bt + (size_t)(n0 + w * 8 + srow8) * K + scol;
    f32x4 acc[MFR][NFR] = {};
    int NT = K >> 6;

    {   // prologue: stage tile 0 into buf 0
        int kn = 0, nb = 0;
        STAGE_ALL;
    }

    #pragma unroll 2
    for (int t = 0; t < NT; ++t) {
        int c = t & 1, nb = c ^ 1;
        int kn = (t + 1) << 6;
        bool last = (t == NT - 1);
        bf16x8 af0[MFR / 2][2], af1[MFR / 2][2], bfr[NFR][2];
        // ---- tile top: issue ALL loads of tile t+1; drain exactly tile t's ----
        if (!last) {
            STAGE_ALL;
            asm volatile("s_waitcnt vmcnt(%0)" :: "n"(LPT) : "memory");
        } else {
            asm volatile("s_waitcnt vmcnt(0)" ::: "memory");
        }
        __builtin_amdgcn_s_barrier();
        // ---- interleaved reads + MFMA (counted lgkmcnt by compiler) ----
        RD_AF(0, af0);
        #pragma unroll
        for (int nf = 0; nf < NFR; ++nf) {
            RD_BF1(nf);
            __builtin_amdgcn_s_setprio(1);
            MMAH(0, nf, af0);
            __builtin_amdgcn_s_setprio(0);
        }
        RD_AF(1, af1);
        __builtin_amdgcn_s_setprio(1);
        #pragma unroll
        for (int nf = 0; nf < NFR; ++nf)
            MMAH(1, nf, af1);
        __builtin_amdgcn_s_setprio(0);
        // ---- tile end: all reads of buf c sampled; next tile may overwrite ----
        __builtin_amdgcn_s_barrier();
    }

    #pragma unroll
    for (int m = 0; m < MFR; ++m)
        #pragma unroll
        for (int n = 0; n < NFR; ++n)
            #pragma unroll
            for (int e = 0; e < 4; ++e) {
                int row = m0 + wm * (MFR * 16) + m * 16 + lg * 4 + e;
                int col = n0 + wn * (NFR * 16) + n * 16 + lr;
                if constexpr (sizeof(OutT) == 4)
                    C[(size_t)row * ldc + col] = acc[m][n][e];
                else
                    C[(size_t)row * ldc + col] = f2b(acc[m][n][e]);
            }
}

// QKV fused: QKVb[2048][6144]. 128x192 tiles, grid 512 = 16 m x 32 n -> 2 blocks/CU (LDS 80KB).
__global__ __launch_bounds__(512, 2) void k_gemm_qkv(const u16* __restrict__ hsb,
        const u16* __restrict__ WqkvT, u16* __restrict__ QKVb) {
    int bid = blockIdx.x;
    int ord = (bid & 7) * 64 + (bid >> 3);   // XCD swizzle (512 % 8 == 0)
    int mt = ord >> 5, nt = ord & 31;
    gemm_core<4, 3, u16>(hsb, WqkvT, QKVb, 4096, 6144, mt * 128, nt * 192);
}

// Out-proj: 128x128 tiles, grid 512 = 16 m x 32 n -> 2 blocks/CU (LDS 64KB).
__global__ __launch_bounds__(512, 2) void k_gemm_out(const u16* __restrict__ Ob, const u16* __restrict__ WoT,
                                                     float* __restrict__ out) {
    int bid = blockIdx.x;
    int ord = (bid & 7) * 64 + (bid >> 3);   // XCD swizzle (512 % 8 == 0)
    int mt = ord >> 5, nt = ord & 31;
    gemm_core<4, 2, float>(Ob, WoT, out, 4096, 4096, mt * 128, nt * 128);
}

// ---------------- RoPE in-place on QKVb: Q (32 heads) and K (8 heads) ----------------
__global__ __launch_bounds__(256) void k_rope(u16* __restrict__ QKV) {
    int t = blockIdx.x * 256 + threadIdx.x;
    int i = t & 63;
    int rest = t >> 6;
    int head = rest % 40;
    int s = rest / 40;
    if (s >= 2048) return;
    u16* base = (head < 32) ? (QKV + (size_t)s * 6144 + head * 128)
                            : (QKV + (size_t)s * 6144 + 4096 + (head - 32) * 128);
    float inv = exp2f((float)i * (-13.287712379549449f / 64.0f));
    float fr = (float)s * inv;
    float sn, cs;
    sincosf(fr, &sn, &cs);
    float x1 = b2f(base[i]), x2 = b2f(base[i + 64]);
    base[i]      = f2b(x1 * cs - x2 * sn);
    base[i + 64] = f2b(x2 * cs + x1 * sn);
}

// ---------------- Flash attention v5 (best measured): max-free softmax ----------------
__global__ __launch_bounds__(256, 2) void k_attn(const u16* __restrict__ QKV,
                                                 const u16* __restrict__ VT, u16* __restrict__ O) {
    __shared__ u16 Kl[2][64][128];   // 32 KB
    __shared__ u16 VTl[128][64];     // 16 KB
    __shared__ u16 Pl[4][32][68];    // 17 KB
    int bid = blockIdx.x;
    int kh = bid & 7;                // XCD-affine kv-head
    int x = bid >> 3;
    int j = x >> 2;
    int h = kh * 4 + (x & 3);
    int qb = (j < 8) ? j : 23 - j;   // pairs (qb, 15-qb): balanced work
    int q0 = qb * 128;
    int t = threadIdx.x, l = t & 63, w = t >> 6;
    int lr = l & 15, lg = l >> 4;
    const float cexp = 0.12751742f;  // log2(e)/sqrt(128)
    const u16* Kh = QKV + 4096 + kh * 128;         // row stride 6144
    const u16* VTh = VT + (size_t)kh * 262144;     // [128][2048]

#define ATT_STAGE_K(B, KV0) do { \
    _Pragma("unroll") for (int i_ = 0; i_ < 4; ++i_) { \
        int r0_ = w * 16 + i_ * 4; \
        int row_ = r0_ + (l >> 4); \
        gload16(Kh + (size_t)((KV0) + row_) * 6144 + ((l & 15) ^ (row_ & 7)) * 8, \
                &Kl[B][r0_][0]); \
    } } while (0)
#define ATT_STAGE_V(KV0) do { \
    _Pragma("unroll") for (int i_ = 0; i_ < 4; ++i_) { \
        int r0_ = w * 32 + i_ * 8; \
        int row_ = r0_ + (l >> 3); \
        gload16(VTh + (size_t)row_ * 2048 + (KV0) + ((l & 7) ^ (row_ & 7)) * 8, \
                &VTl[r0_][0]); \
    } } while (0)

    bf16x8 qf[2][4];
    #pragma unroll
    for (int rb = 0; rb < 2; ++rb) {
        size_t qoff = (size_t)(q0 + w * 32 + rb * 16 + lr) * 6144 + h * 128 + lg * 8;
        #pragma unroll
        for (int d = 0; d < 4; ++d)
            qf[rb][d] = *(const bf16x8*)(QKV + qoff + d * 32);
    }
    bf16x8 ones;
    #pragma unroll
    for (int i = 0; i < 8; ++i) ones[i] = (__bf16)1.0f;

    f32x4 oacc[2][8] = {};
    f32x4 osum[2] = {};

    int ntiles = 2 * qb + 2;
    int rowmax = q0 + w * 32 + 31;

    ATT_STAGE_K(0, 0);               // prologue: K tile 0 -> buf 0

    for (int kt = 0; kt < ntiles; ++kt) {
        int ck = kt & 1;
        int kv0 = kt * 64;
        bool compute = (kv0 <= rowmax);
        bool more = (kt + 1 < ntiles);
        asm volatile("s_waitcnt vmcnt(0)" ::: "memory");
        __builtin_amdgcn_s_barrier();
        ATT_STAGE_V(kv0);
        if (more) ATT_STAGE_K(ck ^ 1, kv0 + 64);
        __builtin_amdgcn_sched_barrier(0);

        f32x4 sacc[2][4] = {};
        if (compute) {
            // ---- QK^T: d-slice OUTER so same-sacc MFMAs are 8 apart ----
            #pragma unroll
            for (int d = 0; d < 4; ++d) {
                bf16x8 kf[4];
                #pragma unroll
                for (int cb = 0; cb < 4; ++cb)
                    kf[cb] = *(const bf16x8*)&Kl[ck][cb * 16 + lr][((d * 4 + lg) ^ (lr & 7)) * 8];
                #pragma unroll
                for (int cb = 0; cb < 4; ++cb) {
                    sacc[0][cb] = __builtin_amdgcn_mfma_f32_16x16x32_bf16(qf[0][d], kf[cb], sacc[0][cb], 0, 0, 0);
                    sacc[1][cb] = __builtin_amdgcn_mfma_f32_16x16x32_bf16(qf[1][d], kf[cb], sacc[1][cb], 0, 0, 0);
                }
            }
            if (kt >= 2 * qb) {
                #pragma unroll
                for (int rb = 0; rb < 2; ++rb)
                    #pragma unroll
                    for (int cb = 0; cb < 4; ++cb)
                        #pragma unroll
                        for (int e = 0; e < 4; ++e) {
                            int row = q0 + w * 32 + rb * 16 + lg * 4 + e;
                            int col = kv0 + cb * 16 + lr;
                            if (col > row) sacc[rb][cb][e] = -3.0e38f;
                        }
            }
            // ---- P = exp2(S*c), native bf16 convert, straight to LDS ----
            #pragma unroll
            for (int rb = 0; rb < 2; ++rb)
                #pragma unroll
                for (int cb = 0; cb < 4; ++cb)
                    #pragma unroll
                    for (int e = 0; e < 4; ++e)
                        Pl[w][rb * 16 + lg * 4 + e][cb * 16 + lr] =
                            f2b_hw(exp2f(sacc[rb][cb][e] * cexp));
        }
        if (more) asm volatile("s_waitcnt vmcnt(4)" ::: "memory");
        else      asm volatile("s_waitcnt vmcnt(0)" ::: "memory");
        __builtin_amdgcn_s_barrier();
        if (compute) {
            asm volatile("s_waitcnt lgkmcnt(0)" ::: "memory");
            __builtin_amdgcn_sched_barrier(0);
            __builtin_amdgcn_s_setprio(1);
            #pragma unroll
            for (int ks = 0; ks < 2; ++ks) {
                bf16x8 pf0 = *(const bf16x8*)&Pl[w][lr][ks * 32 + lg * 8];
                bf16x8 pf1 = *(const bf16x8*)&Pl[w][16 + lr][ks * 32 + lg * 8];
                osum[0] = __builtin_amdgcn_mfma_f32_16x16x32_bf16(pf0, ones, osum[0], 0, 0, 0);
                osum[1] = __builtin_amdgcn_mfma_f32_16x16x32_bf16(pf1, ones, osum[1], 0, 0, 0);
                #pragma unroll
                for (int db = 0; db < 8; ++db) {
                    bf16x8 vf = *(const bf16x8*)&VTl[db * 16 + lr][((ks * 4 + lg) ^ (lr & 7)) * 8];
                    oacc[0][db] = __builtin_amdgcn_mfma_f32_16x16x32_bf16(pf0, vf, oacc[0][db], 0, 0, 0);
                    oacc[1][db] = __builtin_amdgcn_mfma_f32_16x16x32_bf16(pf1, vf, oacc[1][db], 0, 0, 0);
                }
            }
            __builtin_amdgcn_s_setprio(0);
        }
    }
    #pragma unroll
    for (int rb = 0; rb < 2; ++rb)
        #pragma unroll
        for (int db = 0; db < 8; ++db)
            #pragma unroll
            for (int e = 0; e < 4; ++e) {
                int row = q0 + w * 32 + rb * 16 + lg * 4 + e;
                O[(size_t)row * 4096 + h * 128 + db * 16 + lr] = f2b(oacc[rb][db][e] / osum[rb][e]);
            }
#undef ATT_STAGE_K
#undef ATT_STAGE_V
}

extern "C" void kernel_launch(void* const* d_in, const int* in_sizes, int n_in,
                              void* d_out, int out_size, void* d_ws, size_t ws_size,
                              hipStream_t stream) {
    const float* hs = (const float*)d_in[0];
    const float* Wq = (const float*)d_in[1];
    const float* Wk = (const float*)d_in[2];
    const float* Wv = (const float*)d_in[3];
    const float* Wo = (const float*)d_in[4];
    float* out = (float*)d_out;
    char* ws = (char*)d_ws;
    // layout (peak 92.3 MB):
    u16* hsb   = (u16*)(ws);              // [2048][4096] 16.78MB; later Ob
    u16* WqkvT = (u16*)(ws + 16777216);   // [6144][4096] 50.33MB; later VTb+WoT
    u16* QKVb  = (u16*)(ws + 67108864);   // [2048][6144] 25.17MB

    k_cast<<<4096, 256, 0, stream>>>(hs, hsb, 2048 * 4096);
    k_transpose<<<dim3(64, 64), 256, 0, stream>>>(Wq, WqkvT, 4096, 4096);
    k_transpose<<<dim3(16, 64), 256, 0, stream>>>(Wk, WqkvT + (size_t)4096 * 4096, 4096, 1024);
    k_transpose<<<dim3(16, 64), 256, 0, stream>>>(Wv, WqkvT + (size_t)5120 * 4096, 4096, 1024);
    k_gemm_qkv<<<512, 512, 0, stream>>>(hsb, WqkvT, QKVb);
    k_rope<<<20480, 256, 0, stream>>>(QKVb);
    u16* VTb = WqkvT;                         // WqkvT dead after QKV gemm (4.19MB)
    k_vt<<<dim3(2, 32, 8), 256, 0, stream>>>(QKVb, VTb);
    u16* WoT = WqkvT + (size_t)2097152;       // +4.19MB region, 33.55MB, fits in WqkvT
    k_transpose<<<dim3(64, 64), 256, 0, stream>>>(Wo, WoT, 4096, 4096);
    u16* Ob = hsb;                            // hsb dead after QKV gemm
    k_attn<<<512, 256, 0, stream>>>(QKVb, VTb, Ob);
    k_gemm_out<<<512, 512, 0, stream>>>(Ob, WoT, out);
}

// Round 18
// 331.219 us; speedup vs baseline: 1.1516x; 1.0016x over previous
//
#include <hip/hip_runtime.h>
#include <stdint.h>

typedef float f32x4 __attribute__((ext_vector_type(4)));
typedef __bf16 bf16x8 __attribute__((ext_vector_type(8)));
typedef unsigned short u16;
typedef unsigned short u16x8 __attribute__((ext_vector_type(8)));

__device__ __forceinline__ u16 f2b(float f) {
    union { float f; unsigned u; } v; v.f = f;
    return (u16)((v.u + 0x7fffu + ((v.u >> 16) & 1u)) >> 16);
}
__device__ __forceinline__ float b2f(u16 b) {
    union { unsigned u; float f; } v; v.u = ((unsigned)b) << 16;
    return v.f;
}
__device__ __forceinline__ u16 f2b_hw(float f) {      // native convert (1 VALU op)
    __bf16 h = (__bf16)f;
    return __builtin_bit_cast(u16, h);
}

__device__ __forceinline__ void gload16(const u16* g, u16* s) {
    __builtin_amdgcn_global_load_lds((const __attribute__((address_space(1))) void*)g,
                                     (__attribute__((address_space(3))) void*)s, 16, 0, 0);
}

// ---------------- cast fp32 -> bf16 (8 elems/thread) ----------------
__global__ __launch_bounds__(256) void k_cast(const float* __restrict__ src, u16* __restrict__ dst, int n) {
    int i = (blockIdx.x * 256 + threadIdx.x) * 8;
    if (i >= n) return;
    const float4* s = (const float4*)(src + i);
    float4 a = s[0], b = s[1];
    u16x8 o;
    o[0] = f2b(a.x); o[1] = f2b(a.y); o[2] = f2b(a.z); o[3] = f2b(a.w);
    o[4] = f2b(b.x); o[5] = f2b(b.y); o[6] = f2b(b.z); o[7] = f2b(b.w);
    *(u16x8*)(dst + i) = o;
}

// ---------- transpose + cast: src[R][C] f32 -> dst[C][R] bf16, u32-packed writes ----------
__global__ __launch_bounds__(256) void k_transpose(const float* __restrict__ src, u16* __restrict__ dst,
                                                   int R, int C) {
    __shared__ float tile[64][65];
    int c0 = blockIdx.x * 64, r0 = blockIdx.y * 64;
    int tx = threadIdx.x & 63, ty = threadIdx.x >> 6;
    #pragma unroll
    for (int r = ty; r < 64; r += 4)
        tile[r][tx] = src[(size_t)(r0 + r) * C + (c0 + tx)];
    __syncthreads();
    int hx = threadIdx.x & 31, ty8 = threadIdx.x >> 5;
    #pragma unroll
    for (int r = ty8; r < 64; r += 8) {
        unsigned v = (unsigned)f2b(tile[hx * 2][r]) | ((unsigned)f2b(tile[hx * 2 + 1][r]) << 16);
        *(unsigned*)&dst[(size_t)(c0 + r) * R + (r0 + hx * 2)] = v;   // 256B/wave, full line
    }
}

// ------------- bf16 transpose: QKVb V-columns -> VT[8][128][2048] -------------
__global__ __launch_bounds__(256) void k_vt(const u16* __restrict__ QKV, u16* __restrict__ VT) {
    __shared__ u16 tile[64][66];
    int kh = blockIdx.z;
    int s0 = blockIdx.y * 64;
    int d0 = blockIdx.x * 64;
    int tx = threadIdx.x & 63, ty = threadIdx.x >> 6;
    #pragma unroll
    for (int r = ty; r < 64; r += 4)
        tile[r][tx] = QKV[(size_t)(s0 + r) * 6144 + 5120 + kh * 128 + d0 + tx];
    __syncthreads();
    #pragma unroll
    for (int r = ty; r < 64; r += 4)
        VT[(size_t)kh * 262144 + (size_t)(d0 + r) * 2048 + s0 + tx] = tile[tx][r];
}

// ====== (MFR*32) x (NFR*64) GEMM core, BK=64, 8 waves (2M x 4N), full-tile prefetch ======
#define STAGE_A(h) do { \
    _Pragma("unroll") for (int i_ = 0; i_ < MFR / 4; ++i_) \
        gload16(gA + (size_t)((h) * (MFR * 16) + i_ * 8) * K + kn, &Ah[nb][h][w * (MFR * 2) + i_ * 8][0]); \
} while (0)
#define STAGE_B1(h) gload16(gB + (size_t)((h) * 64) * K + kn, &Bh[nb][h][w * 8][0])
#define STAGE_ALL do { \
    _Pragma("unroll") for (int h_ = 0; h_ < 2; ++h_) STAGE_A(h_); \
    _Pragma("unroll") for (int h_ = 0; h_ < NFR; ++h_) STAGE_B1(h_); } while (0)
#define RD_AF(MH, AF) do { \
    _Pragma("unroll") for (int mm = 0; mm < MFR / 2; ++mm) \
    _Pragma("unroll") for (int x = 0; x < 2; ++x) \
        AF[mm][x] = *(const bf16x8*)&Ah[c][wm][((MH) * (MFR / 2) + mm) * 16 + lr][(x * 32 + lk) ^ swz]; } while (0)
#define RD_BF1(NF) do { \
    int bc_ = wn * (NFR * 16) + (NF) * 16; \
    _Pragma("unroll") for (int x = 0; x < 2; ++x) \
        bfr[NF][x] = *(const bf16x8*)&Bh[c][bc_ >> 6][(bc_ & 63) + lr][(x * 32 + lk) ^ swz]; } while (0)
#define MMAH(MH, NF, AF) do { \
    _Pragma("unroll") for (int x = 0; x < 2; ++x) \
    _Pragma("unroll") for (int mm = 0; mm < MFR / 2; ++mm) \
        acc[(MH) * (MFR / 2) + mm][NF] = __builtin_amdgcn_mfma_f32_16x16x32_bf16( \
            AF[mm][x], bfr[NF][x], acc[(MH) * (MFR / 2) + mm][NF], 0, 0, 0); } while (0)

template <int MFR, int NFR, typename OutT>
__device__ __forceinline__ void gemm_core(const u16* __restrict__ A, const u16* __restrict__ Bt,
                                          OutT* __restrict__ C, int K, int ldc, int m0, int n0) {
    __shared__ u16 Ah[2][2][MFR * 16][64];
    __shared__ u16 Bh[2][NFR][64][64];
    constexpr int LPT = MFR / 2 + NFR;   // loads/thread/tile
    int tid = threadIdx.x;
    int l = tid & 63, w = tid >> 6;
    int wm = w >> 2, wn = w & 3;
    int lr = l & 15, lg = l >> 4, lk = lg * 8;
    int swz = (lr & 7) << 3;
    int srow8 = l >> 3;
    int scol = ((l & 7) ^ srow8) * 8;
    const u16* gA = A  + (size_t)(m0 + w * (MFR * 2) + srow8) * K + scol;
    const u16* gB = Bt + (size_t)(n0 + w * 8 + srow8) * K + scol;
    f32x4 acc[MFR][NFR] = {};
    int NT = K >> 6;

    {   // prologue: stage tile 0 into buf 0
        int kn = 0, nb = 0;
        STAGE_ALL;
    }

    #pragma unroll 2
    for (int t = 0; t < NT; ++t) {
        int c = t & 1, nb = c ^ 1;
        int kn = (t + 1) << 6;
        bool last = (t == NT - 1);
        bf16x8 af0[MFR / 2][2], af1[MFR / 2][2], bfr[NFR][2];
        // ---- tile top: issue ALL loads of tile t+1; drain exactly tile t's ----
        if (!last) {
            STAGE_ALL;
            asm volatile("s_waitcnt vmcnt(%0)" :: "n"(LPT) : "memory");
        } else {
            asm volatile("s_waitcnt vmcnt(0)" ::: "memory");
        }
        __builtin_amdgcn_s_barrier();
        // ---- interleaved reads + MFMA (counted lgkmcnt by compiler) ----
        RD_AF(0, af0);
        #pragma unroll
        for (int nf = 0; nf < NFR; ++nf) {
            RD_BF1(nf);
            __builtin_amdgcn_s_setprio(1);
            MMAH(0, nf, af0);
            __builtin_amdgcn_s_setprio(0);
        }
        RD_AF(1, af1);
        __builtin_amdgcn_s_setprio(1);
        #pragma unroll
        for (int nf = 0; nf < NFR; ++nf)
            MMAH(1, nf, af1);
        __builtin_amdgcn_s_setprio(0);
        // ---- tile end: all reads of buf c sampled; next tile may overwrite ----
        __builtin_amdgcn_s_barrier();
    }

    #pragma unroll
    for (int m = 0; m < MFR; ++m)
        #pragma unroll
        for (int n = 0; n < NFR; ++n)
            #pragma unroll
            for (int e = 0; e < 4; ++e) {
                int row = m0 + wm * (MFR * 16) + m * 16 + lg * 4 + e;
                int col = n0 + wn * (NFR * 16) + n * 16 + lr;
                if constexpr (sizeof(OutT) == 4)
                    C[(size_t)row * ldc + col] = acc[m][n][e];
                else
                    C[(size_t)row * ldc + col] = f2b(acc[m][n][e]);
            }
}

// QKV fused: QKVb[2048][6144]. 128x192 tiles, grid 512 = 16 m x 32 n -> 2 blocks/CU (LDS 80KB).
__global__ __launch_bounds__(512, 2) void k_gemm_qkv(const u16* __restrict__ hsb,
        const u16* __restrict__ WqkvT, u16* __restrict__ QKVb) {
    int bid = blockIdx.x;
    int ord = (bid & 7) * 64 + (bid >> 3);   // XCD swizzle (512 % 8 == 0)
    int mt = ord >> 5, nt = ord & 31;
    gemm_core<4, 3, u16>(hsb, WqkvT, QKVb, 4096, 6144, mt * 128, nt * 192);
}

// Out-proj: 128x128 tiles, grid 512 = 16 m x 32 n -> 2 blocks/CU (LDS 64KB).
__global__ __launch_bounds__(512, 2) void k_gemm_out(const u16* __restrict__ Ob, const u16* __restrict__ WoT,
                                                     float* __restrict__ out) {
    int bid = blockIdx.x;
    int ord = (bid & 7) * 64 + (bid >> 3);   // XCD swizzle (512 % 8 == 0)
    int mt = ord >> 5, nt = ord & 31;
    gemm_core<4, 2, float>(Ob, WoT, out, 4096, 4096, mt * 128, nt * 128);
}

// ---------------- RoPE in-place on QKVb: Q (32 heads) and K (8 heads) ----------------
__global__ __launch_bounds__(256) void k_rope(u16* __restrict__ QKV) {
    int t = blockIdx.x * 256 + threadIdx.x;
    int i = t & 63;
    int rest = t >> 6;
    int head = rest % 40;
    int s = rest / 40;
    if (s >= 2048) return;
    u16* base = (head < 32) ? (QKV + (size_t)s * 6144 + head * 128)
                            : (QKV + (size_t)s * 6144 + 4096 + (head - 32) * 128);
    float inv = exp2f((float)i * (-13.287712379549449f / 64.0f));
    float fr = (float)s * inv;
    float sn, cs;
    sincosf(fr, &sn, &cs);
    float x1 = b2f(base[i]), x2 = b2f(base[i + 64]);
    base[i]      = f2b(x1 * cs - x2 * sn);
    base[i + 64] = f2b(x2 * cs + x1 * sn);
}

// ---------------- Flash attention v5 + LPT launch order (longest blocks first) ----------------
__global__ __launch_bounds__(256, 2) void k_attn(const u16* __restrict__ QKV,
                                                 const u16* __restrict__ VT, u16* __restrict__ O) {
    __shared__ u16 Kl[2][64][128];   // 32 KB
    __shared__ u16 VTl[128][64];     // 16 KB
    __shared__ u16 Pl[4][32][68];    // 17 KB
    int bid = blockIdx.x;
    int kh = bid & 7;                // XCD-affine kv-head
    int x = bid >> 3;
    int j = x >> 2;
    int h = kh * 4 + (x & 3);
    // LPT: launch qb DESCENDING (j<8 -> 15..8, j>=8 -> 0..7) so the 32-tile blocks
    // start first and short blocks backfill the tail (same bijection as before).
    int qb = (j < 8) ? 15 - j : j - 8;
    int q0 = qb * 128;
    int t = threadIdx.x, l = t & 63, w = t >> 6;
    int lr = l & 15, lg = l >> 4;
    const float cexp = 0.12751742f;  // log2(e)/sqrt(128)
    const u16* Kh = QKV + 4096 + kh * 128;         // row stride 6144
    const u16* VTh = VT + (size_t)kh * 262144;     // [128][2048]

#define ATT_STAGE_K(B, KV0) do { \
    _Pragma("unroll") for (int i_ = 0; i_ < 4; ++i_) { \
        int r0_ = w * 16 + i_ * 4; \
        int row_ = r0_ + (l >> 4); \
        gload16(Kh + (size_t)((KV0) + row_) * 6144 + ((l & 15) ^ (row_ & 7)) * 8, \
                &Kl[B][r0_][0]); \
    } } while (0)
#define ATT_STAGE_V(KV0) do { \
    _Pragma("unroll") for (int i_ = 0; i_ < 4; ++i_) { \
        int r0_ = w * 32 + i_ * 8; \
        int row_ = r0_ + (l >> 3); \
        gload16(VTh + (size_t)row_ * 2048 + (KV0) + ((l & 7) ^ (row_ & 7)) * 8, \
                &VTl[r0_][0]); \
    } } while (0)

    bf16x8 qf[2][4];
    #pragma unroll
    for (int rb = 0; rb < 2; ++rb) {
        size_t qoff = (size_t)(q0 + w * 32 + rb * 16 + lr) * 6144 + h * 128 + lg * 8;
        #pragma unroll
        for (int d = 0; d < 4; ++d)
            qf[rb][d] = *(const bf16x8*)(QKV + qoff + d * 32);
    }
    bf16x8 ones;
    #pragma unroll
    for (int i = 0; i < 8; ++i) ones[i] = (__bf16)1.0f;

    f32x4 oacc[2][8] = {};
    f32x4 osum[2] = {};

    int ntiles = 2 * qb + 2;
    int rowmax = q0 + w * 32 + 31;

    ATT_STAGE_K(0, 0);               // prologue: K tile 0 -> buf 0

    for (int kt = 0; kt < ntiles; ++kt) {
        int ck = kt & 1;
        int kv0 = kt * 64;
        bool compute = (kv0 <= rowmax);
        bool more = (kt + 1 < ntiles);
        asm volatile("s_waitcnt vmcnt(0)" ::: "memory");
        __builtin_amdgcn_s_barrier();
        ATT_STAGE_V(kv0);
        if (more) ATT_STAGE_K(ck ^ 1, kv0 + 64);
        __builtin_amdgcn_sched_barrier(0);

        f32x4 sacc[2][4] = {};
        if (compute) {
            // ---- QK^T: d-slice OUTER so same-sacc MFMAs are 8 apart ----
            #pragma unroll
            for (int d = 0; d < 4; ++d) {
                bf16x8 kf[4];
                #pragma unroll
                for (int cb = 0; cb < 4; ++cb)
                    kf[cb] = *(const bf16x8*)&Kl[ck][cb * 16 + lr][((d * 4 + lg) ^ (lr & 7)) * 8];
                #pragma unroll
                for (int cb = 0; cb < 4; ++cb) {
                    sacc[0][cb] = __builtin_amdgcn_mfma_f32_16x16x32_bf16(qf[0][d], kf[cb], sacc[0][cb], 0, 0, 0);
                    sacc[1][cb] = __builtin_amdgcn_mfma_f32_16x16x32_bf16(qf[1][d], kf[cb], sacc[1][cb], 0, 0, 0);
                }
            }
            if (kt >= 2 * qb) {
                #pragma unroll
                for (int rb = 0; rb < 2; ++rb)
                    #pragma unroll
                    for (int cb = 0; cb < 4; ++cb)
                        #pragma unroll
                        for (int e = 0; e < 4; ++e) {
                            int row = q0 + w * 32 + rb * 16 + lg * 4 + e;
                            int col = kv0 + cb * 16 + lr;
                            if (col > row) sacc[rb][cb][e] = -3.0e38f;
                        }
            }
            // ---- P = exp2(S*c), native bf16 convert, straight to LDS ----
            #pragma unroll
            for (int rb = 0; rb < 2; ++rb)
                #pragma unroll
                for (int cb = 0; cb < 4; ++cb)
                    #pragma unroll
                    for (int e = 0; e < 4; ++e)
                        Pl[w][rb * 16 + lg * 4 + e][cb * 16 + lr] =
                            f2b_hw(exp2f(sacc[rb][cb][e] * cexp));
        }
        if (more) asm volatile("s_waitcnt vmcnt(4)" ::: "memory");
        else      asm volatile("s_waitcnt vmcnt(0)" ::: "memory");
        __builtin_amdgcn_s_barrier();
        if (compute) {
            asm volatile("s_waitcnt lgkmcnt(0)" ::: "memory");
            __builtin_amdgcn_sched_barrier(0);
            __builtin_amdgcn_s_setprio(1);
            #pragma unroll
            for (int ks = 0; ks < 2; ++ks) {
                bf16x8 pf0 = *(const bf16x8*)&Pl[w][lr][ks * 32 + lg * 8];
                bf16x8 pf1 = *(const bf16x8*)&Pl[w][16 + lr][ks * 32 + lg * 8];
                osum[0] = __builtin_amdgcn_mfma_f32_16x16x32_bf16(pf0, ones, osum[0], 0, 0, 0);
                osum[1] = __builtin_amdgcn_mfma_f32_16x16x32_bf16(pf1, ones, osum[1], 0, 0, 0);
                #pragma unroll
                for (int db = 0; db < 8; ++db) {
                    bf16x8 vf = *(const bf16x8*)&VTl[db * 16 + lr][((ks * 4 + lg) ^ (lr & 7)) * 8];
                    oacc[0][db] = __builtin_amdgcn_mfma_f32_16x16x32_bf16(pf0, vf, oacc[0][db], 0, 0, 0);
                    oacc[1][db] = __builtin_amdgcn_mfma_f32_16x16x32_bf16(pf1, vf, oacc[1][db], 0, 0, 0);
                }
            }
            __builtin_amdgcn_s_setprio(0);
        }
    }
    #pragma unroll
    for (int rb = 0; rb < 2; ++rb)
        #pragma unroll
        for (int db = 0; db < 8; ++db)
            #pragma unroll
            for (int e = 0; e < 4; ++e) {
                int row = q0 + w * 32 + rb * 16 + lg * 4 + e;
                O[(size_t)row * 4096 + h * 128 + db * 16 + lr] = f2b(oacc[rb][db][e] / osum[rb][e]);
            }
#undef ATT_STAGE_K
#undef ATT_STAGE_V
}

extern "C" void kernel_launch(void* const* d_in, const int* in_sizes, int n_in,
                              void* d_out, int out_size, void* d_ws, size_t ws_size,
                              hipStream_t stream) {
    const float* hs = (const float*)d_in[0];
    const float* Wq = (const float*)d_in[1];
    const float* Wk = (const float*)d_in[2];
    const float* Wv = (const float*)d_in[3];
    const float* Wo = (const float*)d_in[4];
    float* out = (float*)d_out;
    char* ws = (char*)d_ws;
    // layout (peak 92.3 MB):
    u16* hsb   = (u16*)(ws);              // [2048][4096] 16.78MB; later Ob
    u16* WqkvT = (u16*)(ws + 16777216);   // [6144][4096] 50.33MB; later VTb+WoT
    u16* QKVb  = (u16*)(ws + 67108864);   // [2048][6144] 25.17MB

    k_cast<<<4096, 256, 0, stream>>>(hs, hsb, 2048 * 4096);
    k_transpose<<<dim3(64, 64), 256, 0, stream>>>(Wq, WqkvT, 4096, 4096);
    k_transpose<<<dim3(16, 64), 256, 0, stream>>>(Wk, WqkvT + (size_t)4096 * 4096, 4096, 1024);
    k_transpose<<<dim3(16, 64), 256, 0, stream>>>(Wv, WqkvT + (size_t)5120 * 4096, 4096, 1024);
    k_gemm_qkv<<<512, 512, 0, stream>>>(hsb, WqkvT, QKVb);
    k_rope<<<20480, 256, 0, stream>>>(QKVb);
    u16* VTb = WqkvT;                         // WqkvT dead after QKV gemm (4.19MB)
    k_vt<<<dim3(2, 32, 8), 256, 0, stream>>>(QKVb, VTb);
    u16* WoT = WqkvT + (size_t)2097152;       // +4.19MB region, 33.55MB, fits in WqkvT
    k_transpose<<<dim3(64, 64), 256, 0, stream>>>(Wo, WoT, 4096, 4096);
    u16* Ob = hsb;                            // hsb dead after QKV gemm
    k_attn<<<512, 256, 0, stream>>>(QKVb, VTb, Ob);
    k_gemm_out<<<512, 512, 0, stream>>>(Ob, WoT, out);
}